// Round 4
// baseline (1012.894 us; speedup 1.0000x reference)
//
#include <hip/hip_runtime.h>
#include <cstddef>

#define LL 2048
#define TOK 8192   // B*L = 4*2048
#define DM 1024
#define DI 2048
#define NS 16

typedef _Float16 half_t;
typedef __attribute__((ext_vector_type(8))) _Float16 f16x8;
typedef __attribute__((ext_vector_type(4))) _Float16 f16x4;
typedef __attribute__((ext_vector_type(4))) float f32x4;

// ---------- helpers ----------
__device__ __forceinline__ float softplus_f(float x) {
  return fmaxf(x, 0.f) + log1pf(__expf(-fabsf(x)));
}
__device__ __forceinline__ float silu_f(float x) {
  return x / (1.f + __expf(-x));
}
__device__ __forceinline__ void gload_lds16(const void* g, void* l) {
  __builtin_amdgcn_global_load_lds((const __attribute__((address_space(1))) void*)g,
                                   (__attribute__((address_space(3))) void*)l, 16, 0, 0);
}
// DPP row_shr add: after ctrl 0x111,0x112,0x114,0x118 lane15 of each row16 holds the row sum
#define DPP_ADD(v, ctrl) \
  ((v) + __int_as_float(__builtin_amdgcn_update_dpp(0, __float_as_int(v), (ctrl), 0xf, 0xf, true)))

// ---------- static scratch (float units) ----------
//  (layout unchanged from prior rounds)
__device__ float g_buf[120881152];

// ---------- fp32 -> fp16 staging ----------
__global__ __launch_bounds__(256) void f2h_k(const float* __restrict__ in,
                                             half_t* __restrict__ out, int n4) {
  const int i = blockIdx.x * 256 + threadIdx.x;
  if (i >= n4) return;
  const float4 v = ((const float4*)in)[i];
  f16x4 o;
  o[0] = (half_t)v.x; o[1] = (half_t)v.y; o[2] = (half_t)v.z; o[3] = (half_t)v.w;
  ((f16x4*)out)[i] = o;
}

// ---------- fp32 -> (hi, lo) fp16 split staging ----------
__global__ __launch_bounds__(256) void f2h2_k(const float* __restrict__ in,
                                              half_t* __restrict__ hi,
                                              half_t* __restrict__ lo, int n4) {
  const int i = blockIdx.x * 256 + threadIdx.x;
  if (i >= n4) return;
  const float4 v = ((const float4*)in)[i];
  f16x4 h, l;
  h[0] = (half_t)v.x; h[1] = (half_t)v.y; h[2] = (half_t)v.z; h[3] = (half_t)v.w;
  l[0] = (half_t)(v.x - (float)h[0]);
  l[1] = (half_t)(v.y - (float)h[1]);
  l[2] = (half_t)(v.z - (float)h[2]);
  l[3] = (half_t)(v.w - (float)h[3]);
  ((f16x4*)hi)[i] = h;
  ((f16x4*)lo)[i] = l;
}

// ---------- fp16 MFMA GEMM: C[M,N] = act(A[M,K] @ W[N,K]^T + bias), fp32 out --
template <int ACT>   // 0 none, 1 silu
__global__ __launch_bounds__(256) void gemm_mfma(const half_t* __restrict__ A,
                                                 const half_t* __restrict__ W,
                                                 const float* __restrict__ bias,
                                                 float* __restrict__ C,
                                                 int M, int N, int K) {
  __shared__ half_t lA[4096];   // 8 KB
  __shared__ half_t lB[4096];   // 8 KB
  const int tid = threadIdx.x;
  const int bm0 = blockIdx.y * 128, bn0 = blockIdx.x * 128;
  const int lane = tid & 63, wave = tid >> 6;
  const int q = lane >> 4, mr = lane & 15;
  const int wm = (wave >> 1) * 64, wn = (wave & 1) * 64;
  const int flat0 = tid, flat1 = tid + 256;
  const int kc0 = flat0 >> 7, r0 = flat0 & 127;
  const int kc1 = flat1 >> 7, r1 = flat1 & 127;

  f32x4 acc[4][4];
#pragma unroll
  for (int i = 0; i < 4; ++i)
#pragma unroll
    for (int j = 0; j < 4; ++j) acc[i][j] = (f32x4){0.f, 0.f, 0.f, 0.f};

  for (int k0 = 0; k0 < K; k0 += 32) {
    gload_lds16(A + (size_t)(bm0 + r0) * K + k0 + kc0 * 8, lA + (size_t)flat0 * 8);
    gload_lds16(A + (size_t)(bm0 + r1) * K + k0 + kc1 * 8, lA + (size_t)flat1 * 8);
    gload_lds16(W + (size_t)(bn0 + r0) * K + k0 + kc0 * 8, lB + (size_t)flat0 * 8);
    gload_lds16(W + (size_t)(bn0 + r1) * K + k0 + kc1 * 8, lB + (size_t)flat1 * 8);
    __syncthreads();
    f16x8 af[4], bg[4];
#pragma unroll
    for (int t = 0; t < 4; ++t) {
      af[t] = *(const f16x8*)(lA + ((q << 10) + ((wm + t * 16 + mr) << 3)));
      bg[t] = *(const f16x8*)(lB + ((q << 10) + ((wn + t * 16 + mr) << 3)));
    }
#pragma unroll
    for (int i = 0; i < 4; ++i)
#pragma unroll
      for (int j = 0; j < 4; ++j)
        acc[i][j] = __builtin_amdgcn_mfma_f32_16x16x32_f16(af[i], bg[j], acc[i][j], 0, 0, 0);
    __syncthreads();
  }

#pragma unroll
  for (int i = 0; i < 4; ++i) {
#pragma unroll
    for (int j = 0; j < 4; ++j) {
      const int col = bn0 + wn + j * 16 + mr;
      const float bv = bias ? bias[col] : 0.f;
#pragma unroll
      for (int r = 0; r < 4; ++r) {
        const int row = bm0 + wm + i * 16 + q * 4 + r;
        float v = acc[i][j][r] + bv;
        if (ACT == 1) v = silu_f(v);
        C[(size_t)row * N + col] = v;
      }
    }
  }
}

// ---------- fused left+gate GEMM: W = [W_left;W_right] (4096 x 1024) ----------
__global__ __launch_bounds__(256) void gemm_mfma_lg(const half_t* __restrict__ A,
                                                    const half_t* __restrict__ W,
                                                    float* __restrict__ left,
                                                    float* __restrict__ gate) {
  __shared__ half_t lA[4096];
  __shared__ half_t lB[4096];
  const int tid = threadIdx.x;
  const int bm0 = blockIdx.y * 128, bn0 = blockIdx.x * 128;
  const int K = DM;
  const int lane = tid & 63, wave = tid >> 6;
  const int q = lane >> 4, mr = lane & 15;
  const int wm = (wave >> 1) * 64, wn = (wave & 1) * 64;
  const int flat1 = tid + 256;
  const int kc0 = tid >> 7, r0 = tid & 127;
  const int kc1 = flat1 >> 7, r1 = flat1 & 127;

  f32x4 acc[4][4];
#pragma unroll
  for (int i = 0; i < 4; ++i)
#pragma unroll
    for (int j = 0; j < 4; ++j) acc[i][j] = (f32x4){0.f, 0.f, 0.f, 0.f};

  for (int k0 = 0; k0 < K; k0 += 32) {
    gload_lds16(A + (size_t)(bm0 + r0) * K + k0 + kc0 * 8, lA + (size_t)tid * 8);
    gload_lds16(A + (size_t)(bm0 + r1) * K + k0 + kc1 * 8, lA + (size_t)flat1 * 8);
    gload_lds16(W + (size_t)(bn0 + r0) * K + k0 + kc0 * 8, lB + (size_t)tid * 8);
    gload_lds16(W + (size_t)(bn0 + r1) * K + k0 + kc1 * 8, lB + (size_t)flat1 * 8);
    __syncthreads();
    f16x8 af[4], bg[4];
#pragma unroll
    for (int t = 0; t < 4; ++t) {
      af[t] = *(const f16x8*)(lA + ((q << 10) + ((wm + t * 16 + mr) << 3)));
      bg[t] = *(const f16x8*)(lB + ((q << 10) + ((wn + t * 16 + mr) << 3)));
    }
#pragma unroll
    for (int i = 0; i < 4; ++i)
#pragma unroll
      for (int j = 0; j < 4; ++j)
        acc[i][j] = __builtin_amdgcn_mfma_f32_16x16x32_f16(af[i], bg[j], acc[i][j], 0, 0, 0);
    __syncthreads();
  }

  const int is_gate = (bn0 >= DI);
  float* out = is_gate ? gate : left;
  const int cb = bn0 - (is_gate ? DI : 0);
#pragma unroll
  for (int i = 0; i < 4; ++i) {
#pragma unroll
    for (int j = 0; j < 4; ++j) {
      const int col = cb + wn + j * 16 + mr;
#pragma unroll
      for (int r = 0; r < 4; ++r) {
        const int row = bm0 + wm + i * 16 + q * 4 + r;
        float v = acc[i][j][r];
        if (is_gate) v = silu_f(v);
        out[(size_t)row * DI + col] = v;
      }
    }
  }
}

// ---------- 2-term split GEMM, 128x128 tile, 256 threads (4 waves) ----------
// acc += Ah*Wh + Ah*Wl.  Occupancy-first redesign: rounds 0-3 proved schedule
// changes are null at 2 blocks/CU (grid 512); per m102, this structure's
// throughput tracks blocks/CU (1/CU=320 TF, 4/CU=833 TF).  128^2 tile ->
// grid (16,64) = 1024 blocks = 4/CU (launch_bounds(256,4): 16 waves, 96 KB
// LDS across 4 blocks).  Same proven single-buffer 2-barrier loop as
// gemm_mfma, extended to 3 staging panels (A, Wh, Wl, 24 KB).
// XCD-chunked bijective swizzle: the 16 bn-blocks sharing an A panel land on
// one XCD -> A served from its own L2 instead of 8x from L3.
__global__ __launch_bounds__(256, 4) void gemm_mfma_split(const half_t* __restrict__ Ah,
                                                          const half_t* __restrict__ Wh,
                                                          const half_t* __restrict__ Wl,
                                                          const float* __restrict__ bias,
                                                          float* __restrict__ C,
                                                          int M, int N, int K) {
  __shared__ half_t lA[4096];    // [kc4][128][8]  8 KB
  __shared__ half_t lBh[4096];   // 8 KB
  __shared__ half_t lBl[4096];   // 8 KB
  const int tid = threadIdx.x;
  // bijective XCD-chunk swizzle over 1024 blocks (HW round-robins consecutive
  // flat ids across 8 XCDs; give each XCD 128 contiguous logical ids)
  const int flat = blockIdx.y * gridDim.x + blockIdx.x;
  const int lo = (flat >> 3) | ((flat & 7) << 7);
  const int bn0 = (lo & 15) << 7;    // N/128 = 16 column blocks (fast axis)
  const int bm0 = (lo >> 4) << 7;    // M/128 = 64 row blocks
  const int lane = tid & 63, wave = tid >> 6;
  const int q = lane >> 4, mr = lane & 15;
  const int wm = (wave >> 1) * 64, wn = (wave & 1) * 64;
  const int flat1 = tid + 256;
  const int kc0 = tid >> 7, r0 = tid & 127;
  const int kc1 = flat1 >> 7, r1 = flat1 & 127;

  f32x4 acc[4][4];
#pragma unroll
  for (int i = 0; i < 4; ++i)
#pragma unroll
    for (int j = 0; j < 4; ++j) acc[i][j] = (f32x4){0.f, 0.f, 0.f, 0.f};

  for (int k0 = 0; k0 < K; k0 += 32) {
    gload_lds16(Ah + (size_t)(bm0 + r0) * K + k0 + kc0 * 8, lA + (size_t)tid * 8);
    gload_lds16(Ah + (size_t)(bm0 + r1) * K + k0 + kc1 * 8, lA + (size_t)flat1 * 8);
    gload_lds16(Wh + (size_t)(bn0 + r0) * K + k0 + kc0 * 8, lBh + (size_t)tid * 8);
    gload_lds16(Wh + (size_t)(bn0 + r1) * K + k0 + kc1 * 8, lBh + (size_t)flat1 * 8);
    gload_lds16(Wl + (size_t)(bn0 + r0) * K + k0 + kc0 * 8, lBl + (size_t)tid * 8);
    gload_lds16(Wl + (size_t)(bn0 + r1) * K + k0 + kc1 * 8, lBl + (size_t)flat1 * 8);
    __syncthreads();
    f16x8 af[4], bh[4], bl[4];
#pragma unroll
    for (int t = 0; t < 4; ++t) {
      const int o = (q << 10) + ((wm + t * 16 + mr) << 3);
      const int ob = (q << 10) + ((wn + t * 16 + mr) << 3);
      af[t] = *(const f16x8*)(lA + o);
      bh[t] = *(const f16x8*)(lBh + ob);
      bl[t] = *(const f16x8*)(lBl + ob);
    }
    __builtin_amdgcn_s_setprio(1);
#pragma unroll
    for (int i = 0; i < 4; ++i)
#pragma unroll
      for (int j = 0; j < 4; ++j) {
        acc[i][j] = __builtin_amdgcn_mfma_f32_16x16x32_f16(af[i], bh[j], acc[i][j], 0, 0, 0);
        acc[i][j] = __builtin_amdgcn_mfma_f32_16x16x32_f16(af[i], bl[j], acc[i][j], 0, 0, 0);
      }
    __builtin_amdgcn_s_setprio(0);
    __syncthreads();
  }

#pragma unroll
  for (int i = 0; i < 4; ++i) {
#pragma unroll
    for (int j = 0; j < 4; ++j) {
      const int col = bn0 + wn + j * 16 + mr;
      const float bv = bias[col];
#pragma unroll
      for (int r = 0; r < 4; ++r) {
        const int row = bm0 + wm + i * 16 + q * 4 + r;
        float v = softplus_f(acc[i][j][r] + bv);
        v = fminf(fmaxf(v, 1e-4f), 10.f);
        C[(size_t)row * N + col] = v;
      }
    }
  }
}

// ---------- skinny MFMA GEMM for B/C: bc[M,32] = xch @ [W_B;W_C]^T ----------
__global__ __launch_bounds__(256) void bc_mfma(const half_t* __restrict__ A,
                                               const half_t* __restrict__ Wbc,
                                               float* __restrict__ bc) {
  __shared__ half_t lA[4096];   // [kc4][128][8]  8 KB
  __shared__ half_t lB[1024];   // [kc4][32][8]   2 KB
  const int tid = threadIdx.x;
  const int bm0 = blockIdx.x * 128;
  const int lane = tid & 63, wave = tid >> 6;
  const int q = lane >> 4, mr = lane & 15;
  const int wm = wave * 32;
  const int flat1 = tid + 256;
  const int kcA0 = tid >> 7, rA0 = tid & 127;
  const int kcA1 = flat1 >> 7, rA1 = flat1 & 127;
  const int kcB = tid >> 5, rB = tid & 31;   // threads 0..127

  f32x4 acc[2][2];
#pragma unroll
  for (int i = 0; i < 2; ++i)
#pragma unroll
    for (int j = 0; j < 2; ++j) acc[i][j] = (f32x4){0.f, 0.f, 0.f, 0.f};

  for (int k0 = 0; k0 < DI; k0 += 32) {
    gload_lds16(A + (size_t)(bm0 + rA0) * DI + k0 + kcA0 * 8, lA + (size_t)tid * 8);
    gload_lds16(A + (size_t)(bm0 + rA1) * DI + k0 + kcA1 * 8, lA + (size_t)flat1 * 8);
    if (tid < 128)
      gload_lds16(Wbc + (size_t)rB * DI + k0 + kcB * 8, lB + (size_t)tid * 8);
    __syncthreads();
    f16x8 af[2], bg[2];
#pragma unroll
    for (int t = 0; t < 2; ++t) {
      af[t] = *(const f16x8*)(lA + ((q << 10) + ((wm + t * 16 + mr) << 3)));
      bg[t] = *(const f16x8*)(lB + ((q << 8) + ((t * 16 + mr) << 3)));
    }
#pragma unroll
    for (int i = 0; i < 2; ++i)
#pragma unroll
      for (int j = 0; j < 2; ++j)
        acc[i][j] = __builtin_amdgcn_mfma_f32_16x16x32_f16(af[i], bg[j], acc[i][j], 0, 0, 0);
    __syncthreads();
  }

#pragma unroll
  for (int i = 0; i < 2; ++i) {
#pragma unroll
    for (int j = 0; j < 2; ++j) {
#pragma unroll
      for (int r = 0; r < 4; ++r) {
        const int row = bm0 + wm + i * 16 + q * 4 + r;
        bc[(size_t)row * 32 + 2 * mr + j] = acc[i][j][r];
      }
    }
  }
}

// ---------- causal depthwise conv(4) + bias + silu (fp32 + fp16 out) ----------
__global__ __launch_bounds__(256) void conv_silu_k(const float* __restrict__ left,
                                                   const float* __restrict__ cw,
                                                   const float* __restrict__ cb,
                                                   float* __restrict__ xc,
                                                   half_t* __restrict__ xch) {
  const int idx = blockIdx.x * 256 + threadIdx.x;  // over TOK*DI
  const int d = idx & (DI - 1);
  const int bt = idx >> 11;
  const int t = bt & (LL - 1);
  const float4 wv = *(const float4*)(cw + (size_t)d * 4);
  float acc = cb[d];
  const size_t base = (size_t)idx;
  if (t >= 3) {
    acc += left[base - 3 * DI] * wv.x + left[base - 2 * DI] * wv.y +
           left[base - DI] * wv.z + left[base] * wv.w;
  } else {
    acc += left[base] * wv.w;
    if (t >= 1) acc += left[base - DI] * wv.z;
    if (t >= 2) acc += left[base - 2 * DI] * wv.y;
  }
  const float v = silu_f(acc);
  xc[base] = v;
  xch[base] = (half_t)v;
}

// ---------- selective scan: DPP reduce, packed LDS, prefetch pipeline ----------
#define ST 32
__global__ __launch_bounds__(256) void scan_k(const float* __restrict__ delta,
                                              const float* __restrict__ xc,
                                              const float* __restrict__ gate,
                                              const float* __restrict__ bcp,
                                              const float* __restrict__ A_log,
                                              float* __restrict__ y) {
  __shared__ float dx2[16 * 68];
  __shared__ float bcs[ST * 32];
  __shared__ float ys[ST * 16];
  const int tid = threadIdx.x;
  const int b  = blockIdx.x >> 7;
  const int d0 = (blockIdx.x & 127) << 4;
  const int n  = tid & 15;
  const int ch = tid >> 4;
  const float An = -softplus_f(A_log[n]);

  const int t_a = tid >> 4, c_a = tid & 15;
  const int t_b = t_a + 16;

  float h = 0.f;
  const size_t batch_base = (size_t)b * LL * DI + d0;
  const size_t batch_bc   = (size_t)b * LL * 32;

  size_t rb_cur = batch_base;
  float g0, g1;
  {
    const size_t ra = rb_cur + (size_t)t_a * DI + c_a;
    const size_t rbx = rb_cur + (size_t)t_b * DI + c_a;
    const float d0v = delta[ra], x0v = xc[ra];
    const float d1v = delta[rbx], x1v = xc[rbx];
    g0 = gate[ra]; g1 = gate[rbx];
    const float2 b0 = *(const float2*)&bcp[batch_bc + (size_t)t_a * 32 + 2 * c_a];
    const float2 b1 = *(const float2*)&bcp[batch_bc + (size_t)t_b * 32 + 2 * c_a];
    *(float2*)&dx2[c_a * 68 + t_a * 2] = make_float2(d0v, x0v);
    *(float2*)&dx2[c_a * 68 + t_b * 2] = make_float2(d1v, x1v);
    *(float2*)&bcs[t_a * 32 + 2 * c_a] = b0;
    *(float2*)&bcs[t_b * 32 + 2 * c_a] = b1;
  }
  __syncthreads();

  for (int it = 0; it < LL / ST; ++it) {
    float nd0, nx0, ng0, nd1, nx1, ng1;
    float2 nb0, nb1;
    const size_t rb_nxt = batch_base + (size_t)(it + 1) * ST * DI;
    if (it + 1 < LL / ST) {
      const size_t ra = rb_nxt + (size_t)t_a * DI + c_a;
      const size_t rbx = rb_nxt + (size_t)t_b * DI + c_a;
      nd0 = delta[ra]; nx0 = xc[ra]; ng0 = gate[ra];
      nd1 = delta[rbx]; nx1 = xc[rbx]; ng1 = gate[rbx];
      const size_t bcb = batch_bc + (size_t)(it + 1) * ST * 32;
      nb0 = *(const float2*)&bcp[bcb + (size_t)t_a * 32 + 2 * c_a];
      nb1 = *(const float2*)&bcp[bcb + (size_t)t_b * 32 + 2 * c_a];
    }

    const float* dxp = &dx2[ch * 68];
#pragma unroll
    for (int tt = 0; tt < ST; tt += 2) {
      const float4 v = *(const float4*)&dxp[tt * 2];
      const float2 bc0 = *(const float2*)&bcs[tt * 32 + 2 * n];
      const float2 bc1 = *(const float2*)&bcs[(tt + 1) * 32 + 2 * n];
      float ab = __expf(v.x * An);
      h = fmaf(ab, h, v.x * v.y * bc0.x);
      float p = h * bc0.y;
      p = DPP_ADD(p, 0x111); p = DPP_ADD(p, 0x112);
      p = DPP_ADD(p, 0x114); p = DPP_ADD(p, 0x118);
      if (n == 15) ys[tt * 16 + ch] = p;
      ab = __expf(v.z * An);
      h = fmaf(ab, h, v.z * v.w * bc1.x);
      p = h * bc1.y;
      p = DPP_ADD(p, 0x111); p = DPP_ADD(p, 0x112);
      p = DPP_ADD(p, 0x114); p = DPP_ADD(p, 0x118);
      if (n == 15) ys[(tt + 1) * 16 + ch] = p;
    }
    __syncthreads();

    if (it + 1 < LL / ST) {
      *(float2*)&dx2[c_a * 68 + t_a * 2] = make_float2(nd0, nx0);
      *(float2*)&dx2[c_a * 68 + t_b * 2] = make_float2(nd1, nx1);
      *(float2*)&bcs[t_a * 32 + 2 * c_a] = nb0;
      *(float2*)&bcs[t_b * 32 + 2 * c_a] = nb1;
    }
    y[rb_cur + (size_t)t_a * DI + c_a] = ys[t_a * 16 + c_a] * g0;
    y[rb_cur + (size_t)t_b * DI + c_a] = ys[t_b * 16 + c_a] * g1;
    g0 = ng0; g1 = ng1;
    rb_cur = rb_nxt;
    __syncthreads();
  }
}

// ---------- layernorm over d_inner (fp16 out for MFMA consumer) ----------
__global__ __launch_bounds__(256) void ln_k(const float* __restrict__ y,
                                            const float* __restrict__ gam,
                                            const float* __restrict__ bet,
                                            half_t* __restrict__ outn) {
  const int row = blockIdx.x;
  const int tid = threadIdx.x;
  const float* yr = y + (size_t)row * DI;
  const float4 v0 = ((const float4*)yr)[tid];
  const float4 v1 = ((const float4*)yr)[tid + 256];
  float s = v0.x + v0.y + v0.z + v0.w + v1.x + v1.y + v1.z + v1.w;
  float q = v0.x * v0.x + v0.y * v0.y + v0.z * v0.z + v0.w * v0.w +
            v1.x * v1.x + v1.y * v1.y + v1.z * v1.z + v1.w * v1.w;
  for (int off = 32; off > 0; off >>= 1) {
    s += __shfl_down(s, off);
    q += __shfl_down(q, off);
  }
  __shared__ float sred[4], qred[4];
  const int wid = tid >> 6;
  if ((tid & 63) == 0) { sred[wid] = s; qred[wid] = q; }
  __syncthreads();
  s = sred[0] + sred[1] + sred[2] + sred[3];
  q = qred[0] + qred[1] + qred[2] + qred[3];
  const float mu = s * (1.f / DI);
  const float rs = rsqrtf(q * (1.f / DI) - mu * mu + 1e-5f);
  half_t* orow = outn + (size_t)row * DI;
  const int c0 = tid * 4, c1 = (tid + 256) * 4;
  f16x4 o;
  o[0] = (half_t)((v0.x - mu) * rs * gam[c0 + 0] + bet[c0 + 0]);
  o[1] = (half_t)((v0.y - mu) * rs * gam[c0 + 1] + bet[c0 + 1]);
  o[2] = (half_t)((v0.z - mu) * rs * gam[c0 + 2] + bet[c0 + 2]);
  o[3] = (half_t)((v0.w - mu) * rs * gam[c0 + 3] + bet[c0 + 3]);
  ((f16x4*)orow)[tid] = o;
  o[0] = (half_t)((v1.x - mu) * rs * gam[c1 + 0] + bet[c1 + 0]);
  o[1] = (half_t)((v1.y - mu) * rs * gam[c1 + 1] + bet[c1 + 1]);
  o[2] = (half_t)((v1.z - mu) * rs * gam[c1 + 2] + bet[c1 + 2]);
  o[3] = (half_t)((v1.w - mu) * rs * gam[c1 + 3] + bet[c1 + 3]);
  ((f16x4*)orow)[tid + 256] = o;
}

// ---------- host launch ----------
extern "C" void kernel_launch(void* const* d_in, const int* in_sizes, int n_in,
                              void* d_out, int out_size, void* d_ws, size_t ws_size,
                              hipStream_t stream) {
  const float* x       = (const float*)d_in[0];
  const float* W_left  = (const float*)d_in[1];
  const float* conv_w  = (const float*)d_in[2];
  const float* conv_b  = (const float*)d_in[3];
  const float* W_delta = (const float*)d_in[4];
  const float* b_delta = (const float*)d_in[5];
  const float* W_B     = (const float*)d_in[6];
  const float* W_C     = (const float*)d_in[7];
  const float* A_log   = (const float*)d_in[8];
  const float* W_right = (const float*)d_in[9];
  const float* ln_g    = (const float*)d_in[10];
  const float* ln_b    = (const float*)d_in[11];
  const float* W_out   = (const float*)d_in[12];

  float* buf = nullptr;
  hipGetSymbolAddress((void**)&buf, HIP_SYMBOL(g_buf));
  half_t* xh   = (half_t*)(buf + 0);
  half_t* wlgh = (half_t*)(buf + 4194304);   // [W_left;W_right] 4096x1024 fp16
  half_t* wrh  = (half_t*)(buf + 5242880);
  half_t* wdh  = (half_t*)(buf + 6291456);
  half_t* wdl  = (half_t*)(buf + 8388608);
  half_t* woh  = (half_t*)(buf + 10485760);
  float* left  = buf + 11534336;
  float* xc    = buf + 28311552;
  half_t* xch  = (half_t*)(buf + 45088768);
  float* dlt   = buf + 61865984;
  float* gate  = buf + 78643200;
  float* yv    = buf + 95420416;
  half_t* nrmh = (half_t*)(buf + 112197632);
  float* bc    = buf + 120586240;
  half_t* wbch = (half_t*)(buf + 120848384);

  // fp32 -> fp16 staging
  f2h_k<<<8192, 256, 0, stream>>>(x, xh, TOK * DM / 4);
  f2h_k<<<2048, 256, 0, stream>>>(W_left, wlgh, DI * DM / 4);
  f2h_k<<<2048, 256, 0, stream>>>(W_right, wrh, DI * DM / 4);
  f2h_k<<<2048, 256, 0, stream>>>(W_out, woh, DM * DI / 4);
  f2h2_k<<<4096, 256, 0, stream>>>(W_delta, wdh, wdl, DI * DI / 4);
  f2h_k<<<32, 256, 0, stream>>>(W_B, wbch, NS * DI / 4);
  f2h_k<<<32, 256, 0, stream>>>(W_C, wbch + NS * DI, NS * DI / 4);

  // left = x @ W_left^T ; gate = silu(x @ W_right^T)  -- fused, N=4096
  gemm_mfma_lg<<<dim3(2 * DI / 128, TOK / 128), 256, 0, stream>>>(xh, wlgh, left, gate);
  // xc = silu(causal_conv(left))  (fp32 + fp16)
  conv_silu_k<<<TOK * DI / 256, 256, 0, stream>>>(left, conv_w, conv_b, xc, xch);
  // delta = clip(softplus(xc @ W_delta^T + b_delta))  [128^2 tile, 4 blocks/CU]
  gemm_mfma_split<<<dim3(DI / 128, TOK / 128), 256, 0, stream>>>(xch, wdh, wdl, b_delta, dlt, TOK, DI, DI);
  // B/C projections via MFMA (interleaved output)
  bc_mfma<<<TOK / 128, 256, 0, stream>>>(xch, wbch, bc);
  // selective scan with fused gate (DPP reduce + prefetch pipeline)
  scan_k<<<512, 256, 0, stream>>>(dlt, xc, gate, bc, A_log, yv);
  // layernorm -> fp16
  ln_k<<<TOK, 256, 0, stream>>>(yv, ln_g, ln_b, nrmh);
  // out = nrm @ W_out^T  (fp32 store to d_out)
  gemm_mfma<0><<<dim3(DM / 128, TOK / 128), 256, 0, stream>>>(nrmh, woh, nullptr, (float*)d_out, TOK, DM, DI);
}

// Round 5
// 967.901 us; speedup vs baseline: 1.0465x; 1.0465x over previous
//
#include <hip/hip_runtime.h>
#include <cstddef>

#define LL 2048
#define TOK 8192   // B*L = 4*2048
#define DM 1024
#define DI 2048
#define NS 16

typedef _Float16 half_t;
typedef __attribute__((ext_vector_type(8))) _Float16 f16x8;
typedef __attribute__((ext_vector_type(4))) _Float16 f16x4;
typedef __attribute__((ext_vector_type(4))) float f32x4;

// ---------- helpers ----------
__device__ __forceinline__ float softplus_f(float x) {
  return fmaxf(x, 0.f) + log1pf(__expf(-fabsf(x)));
}
__device__ __forceinline__ float silu_f(float x) {
  return x / (1.f + __expf(-x));
}
__device__ __forceinline__ void gload_lds16(const void* g, void* l) {
  __builtin_amdgcn_global_load_lds((const __attribute__((address_space(1))) void*)g,
                                   (__attribute__((address_space(3))) void*)l, 16, 0, 0);
}
// DPP row_shr add: after ctrl 0x111,0x112,0x114,0x118 lane15 of each row16 holds the row sum
#define DPP_ADD(v, ctrl) \
  ((v) + __int_as_float(__builtin_amdgcn_update_dpp(0, __float_as_int(v), (ctrl), 0xf, 0xf, true)))

// ---------- static scratch (float units) ----------
//  (layout unchanged from prior rounds)
__device__ float g_buf[120881152];

// ---------- fp32 -> fp16 staging ----------
__global__ __launch_bounds__(256) void f2h_k(const float* __restrict__ in,
                                             half_t* __restrict__ out, int n4) {
  const int i = blockIdx.x * 256 + threadIdx.x;
  if (i >= n4) return;
  const float4 v = ((const float4*)in)[i];
  f16x4 o;
  o[0] = (half_t)v.x; o[1] = (half_t)v.y; o[2] = (half_t)v.z; o[3] = (half_t)v.w;
  ((f16x4*)out)[i] = o;
}

// ---------- fp32 -> (hi, lo) fp16 split staging ----------
__global__ __launch_bounds__(256) void f2h2_k(const float* __restrict__ in,
                                              half_t* __restrict__ hi,
                                              half_t* __restrict__ lo, int n4) {
  const int i = blockIdx.x * 256 + threadIdx.x;
  if (i >= n4) return;
  const float4 v = ((const float4*)in)[i];
  f16x4 h, l;
  h[0] = (half_t)v.x; h[1] = (half_t)v.y; h[2] = (half_t)v.z; h[3] = (half_t)v.w;
  l[0] = (half_t)(v.x - (float)h[0]);
  l[1] = (half_t)(v.y - (float)h[1]);
  l[2] = (half_t)(v.z - (float)h[2]);
  l[3] = (half_t)(v.w - (float)h[3]);
  ((f16x4*)hi)[i] = h;
  ((f16x4*)lo)[i] = l;
}

// ---------- fp16 MFMA GEMM: C[M,N] = act(A[M,K] @ W[N,K]^T + bias), fp32 out --
template <int ACT>   // 0 none, 1 silu
__global__ __launch_bounds__(256) void gemm_mfma(const half_t* __restrict__ A,
                                                 const half_t* __restrict__ W,
                                                 const float* __restrict__ bias,
                                                 float* __restrict__ C,
                                                 int M, int N, int K) {
  __shared__ half_t lA[4096];   // 8 KB
  __shared__ half_t lB[4096];   // 8 KB
  const int tid = threadIdx.x;
  const int bm0 = blockIdx.y * 128, bn0 = blockIdx.x * 128;
  const int lane = tid & 63, wave = tid >> 6;
  const int q = lane >> 4, mr = lane & 15;
  const int wm = (wave >> 1) * 64, wn = (wave & 1) * 64;
  const int flat0 = tid, flat1 = tid + 256;
  const int kc0 = flat0 >> 7, r0 = flat0 & 127;
  const int kc1 = flat1 >> 7, r1 = flat1 & 127;

  f32x4 acc[4][4];
#pragma unroll
  for (int i = 0; i < 4; ++i)
#pragma unroll
    for (int j = 0; j < 4; ++j) acc[i][j] = (f32x4){0.f, 0.f, 0.f, 0.f};

  for (int k0 = 0; k0 < K; k0 += 32) {
    gload_lds16(A + (size_t)(bm0 + r0) * K + k0 + kc0 * 8, lA + (size_t)flat0 * 8);
    gload_lds16(A + (size_t)(bm0 + r1) * K + k0 + kc1 * 8, lA + (size_t)flat1 * 8);
    gload_lds16(W + (size_t)(bn0 + r0) * K + k0 + kc0 * 8, lB + (size_t)flat0 * 8);
    gload_lds16(W + (size_t)(bn0 + r1) * K + k0 + kc1 * 8, lB + (size_t)flat1 * 8);
    __syncthreads();
    f16x8 af[4], bg[4];
#pragma unroll
    for (int t = 0; t < 4; ++t) {
      af[t] = *(const f16x8*)(lA + ((q << 10) + ((wm + t * 16 + mr) << 3)));
      bg[t] = *(const f16x8*)(lB + ((q << 10) + ((wn + t * 16 + mr) << 3)));
    }
#pragma unroll
    for (int i = 0; i < 4; ++i)
#pragma unroll
      for (int j = 0; j < 4; ++j)
        acc[i][j] = __builtin_amdgcn_mfma_f32_16x16x32_f16(af[i], bg[j], acc[i][j], 0, 0, 0);
    __syncthreads();
  }

#pragma unroll
  for (int i = 0; i < 4; ++i) {
#pragma unroll
    for (int j = 0; j < 4; ++j) {
      const int col = bn0 + wn + j * 16 + mr;
      const float bv = bias ? bias[col] : 0.f;
#pragma unroll
      for (int r = 0; r < 4; ++r) {
        const int row = bm0 + wm + i * 16 + q * 4 + r;
        float v = acc[i][j][r] + bv;
        if (ACT == 1) v = silu_f(v);
        C[(size_t)row * N + col] = v;
      }
    }
  }
}

// ---------- fused left+gate GEMM: W = [W_left;W_right] (4096 x 1024) ----------
__global__ __launch_bounds__(256) void gemm_mfma_lg(const half_t* __restrict__ A,
                                                    const half_t* __restrict__ W,
                                                    float* __restrict__ left,
                                                    float* __restrict__ gate) {
  __shared__ half_t lA[4096];
  __shared__ half_t lB[4096];
  const int tid = threadIdx.x;
  const int bm0 = blockIdx.y * 128, bn0 = blockIdx.x * 128;
  const int K = DM;
  const int lane = tid & 63, wave = tid >> 6;
  const int q = lane >> 4, mr = lane & 15;
  const int wm = (wave >> 1) * 64, wn = (wave & 1) * 64;
  const int flat1 = tid + 256;
  const int kc0 = tid >> 7, r0 = tid & 127;
  const int kc1 = flat1 >> 7, r1 = flat1 & 127;

  f32x4 acc[4][4];
#pragma unroll
  for (int i = 0; i < 4; ++i)
#pragma unroll
    for (int j = 0; j < 4; ++j) acc[i][j] = (f32x4){0.f, 0.f, 0.f, 0.f};

  for (int k0 = 0; k0 < K; k0 += 32) {
    gload_lds16(A + (size_t)(bm0 + r0) * K + k0 + kc0 * 8, lA + (size_t)tid * 8);
    gload_lds16(A + (size_t)(bm0 + r1) * K + k0 + kc1 * 8, lA + (size_t)flat1 * 8);
    gload_lds16(W + (size_t)(bn0 + r0) * K + k0 + kc0 * 8, lB + (size_t)tid * 8);
    gload_lds16(W + (size_t)(bn0 + r1) * K + k0 + kc1 * 8, lB + (size_t)flat1 * 8);
    __syncthreads();
    f16x8 af[4], bg[4];
#pragma unroll
    for (int t = 0; t < 4; ++t) {
      af[t] = *(const f16x8*)(lA + ((q << 10) + ((wm + t * 16 + mr) << 3)));
      bg[t] = *(const f16x8*)(lB + ((q << 10) + ((wn + t * 16 + mr) << 3)));
    }
#pragma unroll
    for (int i = 0; i < 4; ++i)
#pragma unroll
      for (int j = 0; j < 4; ++j)
        acc[i][j] = __builtin_amdgcn_mfma_f32_16x16x32_f16(af[i], bg[j], acc[i][j], 0, 0, 0);
    __syncthreads();
  }

  const int is_gate = (bn0 >= DI);
  float* out = is_gate ? gate : left;
  const int cb = bn0 - (is_gate ? DI : 0);
#pragma unroll
  for (int i = 0; i < 4; ++i) {
#pragma unroll
    for (int j = 0; j < 4; ++j) {
      const int col = cb + wn + j * 16 + mr;
#pragma unroll
      for (int r = 0; r < 4; ++r) {
        const int row = bm0 + wm + i * 16 + q * 4 + r;
        float v = acc[i][j][r];
        if (is_gate) v = silu_f(v);
        out[(size_t)row * DI + col] = v;
      }
    }
  }
}

// ---------- 2-term split GEMM, 256x128 tile, BK=64, 512 threads (8 waves) ----
// Deep-K counted-vmcnt pipeline (T3+T4 minimum-2-phase): see round-5 notes.
__global__ __launch_bounds__(512, 2) void gemm_mfma_split(const half_t* __restrict__ Ah,
                                                          const half_t* __restrict__ Wh,
                                                          const half_t* __restrict__ Wl,
                                                          const float* __restrict__ bias,
                                                          float* __restrict__ C,
                                                          int M, int N, int K) {
  __shared__ half_t lA[2][16384];   // [buf][kc8][256][8]  2x32 KB
  __shared__ half_t lBh[2][8192];   // [buf][kc8][128][8]  2x16 KB
  __shared__ half_t lBl[2][8192];   // 2x16 KB
  const int tid = threadIdx.x;
  const int bm0 = blockIdx.y * 256, bn0 = blockIdx.x * 128;
  const int lane = tid & 63, wave = tid >> 6;
  const int q = lane >> 4, mr = lane & 15;
  const int wm = (wave >> 1) * 64, wn = (wave & 1) * 64;

#define STAGE_S(bufp, kt)                                                                  \
  do {                                                                                     \
    const int kb = (kt) * 64;                                                              \
    _Pragma("unroll")                                                                      \
    for (int l = 0; l < 4; ++l) {                                                          \
      const int fl = l * 512 + tid;                                                        \
      const int kc = fl >> 8, row = fl & 255;                                              \
      gload_lds16(Ah + (size_t)(bm0 + row) * K + kb + kc * 8, &lA[bufp][fl * 8]);          \
    }                                                                                      \
    _Pragma("unroll")                                                                      \
    for (int l = 0; l < 2; ++l) {                                                          \
      const int fl = l * 512 + tid;                                                        \
      const int kc = fl >> 7, row = fl & 127;                                              \
      gload_lds16(Wh + (size_t)(bn0 + row) * K + kb + kc * 8, &lBh[bufp][fl * 8]);         \
      gload_lds16(Wl + (size_t)(bn0 + row) * K + kb + kc * 8, &lBl[bufp][fl * 8]);         \
    }                                                                                      \
  } while (0)

#define COMPUTE_S(bufp, ksub)                                                              \
  do {                                                                                     \
    f16x8 a4[4], bh4[4], bl4[4];                                                           \
    _Pragma("unroll")                                                                      \
    for (int t = 0; t < 4; ++t) {                                                          \
      const int kc = (ksub) * 4 + q;                                                       \
      a4[t] = *(const f16x8*)&lA[bufp][(kc * 256 + wm + t * 16 + mr) * 8];                 \
      bh4[t] = *(const f16x8*)&lBh[bufp][(kc * 128 + wn + t * 16 + mr) * 8];               \
      bl4[t] = *(const f16x8*)&lBl[bufp][(kc * 128 + wn + t * 16 + mr) * 8];               \
    }                                                                                      \
    __builtin_amdgcn_s_setprio(1);                                                         \
    _Pragma("unroll")                                                                      \
    for (int i = 0; i < 4; ++i)                                                            \
      _Pragma("unroll")                                                                    \
      for (int j = 0; j < 4; ++j) {                                                        \
        acc[i][j] = __builtin_amdgcn_mfma_f32_16x16x32_f16(a4[i], bh4[j], acc[i][j], 0, 0, 0); \
        acc[i][j] = __builtin_amdgcn_mfma_f32_16x16x32_f16(a4[i], bl4[j], acc[i][j], 0, 0, 0); \
      }                                                                                    \
    __builtin_amdgcn_s_setprio(0);                                                         \
  } while (0)

  f32x4 acc[4][4];
#pragma unroll
  for (int i = 0; i < 4; ++i)
#pragma unroll
    for (int j = 0; j < 4; ++j) acc[i][j] = (f32x4){0.f, 0.f, 0.f, 0.f};

  STAGE_S(0, 0);

  for (int t = 0; t < 31; ++t) {
    const int cur = t & 1;
    STAGE_S(cur ^ 1, t + 1);                           // 16 outstanding after this
    asm volatile("s_waitcnt vmcnt(8)" ::: "memory");   // tile t's 8 done; t+1's stay
    __builtin_amdgcn_s_barrier();                      // buf[cur] valid for all waves
    COMPUTE_S(cur, 0);
    COMPUTE_S(cur, 1);
    asm volatile("s_waitcnt lgkmcnt(0)" ::: "memory"); // my reads of buf[cur] retired
    __builtin_amdgcn_s_barrier();                      // all waves done with buf[cur]
  }
  asm volatile("s_waitcnt vmcnt(0)" ::: "memory");
  __builtin_amdgcn_s_barrier();
  COMPUTE_S(1, 0);
  COMPUTE_S(1, 1);
#undef STAGE_S
#undef COMPUTE_S

#pragma unroll
  for (int i = 0; i < 4; ++i) {
#pragma unroll
    for (int j = 0; j < 4; ++j) {
      const int col = bn0 + wn + j * 16 + mr;
      const float bv = bias[col];
#pragma unroll
      for (int r = 0; r < 4; ++r) {
        const int row = bm0 + wm + i * 16 + q * 4 + r;
        float v = softplus_f(acc[i][j][r] + bv);
        v = fminf(fmaxf(v, 1e-4f), 10.f);
        C[(size_t)row * N + col] = v;
      }
    }
  }
}

// ---------- skinny MFMA GEMM for B/C: bc[M,32] = xch @ [W_B;W_C]^T ----------
__global__ __launch_bounds__(256) void bc_mfma(const half_t* __restrict__ A,
                                               const half_t* __restrict__ Wbc,
                                               float* __restrict__ bc) {
  __shared__ half_t lA[4096];   // [kc4][128][8]  8 KB
  __shared__ half_t lB[1024];   // [kc4][32][8]   2 KB
  const int tid = threadIdx.x;
  const int bm0 = blockIdx.x * 128;
  const int lane = tid & 63, wave = tid >> 6;
  const int q = lane >> 4, mr = lane & 15;
  const int wm = wave * 32;
  const int flat1 = tid + 256;
  const int kcA0 = tid >> 7, rA0 = tid & 127;
  const int kcA1 = flat1 >> 7, rA1 = flat1 & 127;
  const int kcB = tid >> 5, rB = tid & 31;   // threads 0..127

  f32x4 acc[2][2];
#pragma unroll
  for (int i = 0; i < 2; ++i)
#pragma unroll
    for (int j = 0; j < 2; ++j) acc[i][j] = (f32x4){0.f, 0.f, 0.f, 0.f};

  for (int k0 = 0; k0 < DI; k0 += 32) {
    gload_lds16(A + (size_t)(bm0 + rA0) * DI + k0 + kcA0 * 8, lA + (size_t)tid * 8);
    gload_lds16(A + (size_t)(bm0 + rA1) * DI + k0 + kcA1 * 8, lA + (size_t)flat1 * 8);
    if (tid < 128)
      gload_lds16(Wbc + (size_t)rB * DI + k0 + kcB * 8, lB + (size_t)tid * 8);
    __syncthreads();
    f16x8 af[2], bg[2];
#pragma unroll
    for (int t = 0; t < 2; ++t) {
      af[t] = *(const f16x8*)(lA + ((q << 10) + ((wm + t * 16 + mr) << 3)));
      bg[t] = *(const f16x8*)(lB + ((q << 8) + ((t * 16 + mr) << 3)));
    }
#pragma unroll
    for (int i = 0; i < 2; ++i)
#pragma unroll
      for (int j = 0; j < 2; ++j)
        acc[i][j] = __builtin_amdgcn_mfma_f32_16x16x32_f16(af[i], bg[j], acc[i][j], 0, 0, 0);
    __syncthreads();
  }

#pragma unroll
  for (int i = 0; i < 2; ++i) {
#pragma unroll
    for (int j = 0; j < 2; ++j) {
#pragma unroll
      for (int r = 0; r < 4; ++r) {
        const int row = bm0 + wm + i * 16 + q * 4 + r;
        bc[(size_t)row * 32 + 2 * mr + j] = acc[i][j][r];
      }
    }
  }
}

// ---------- causal depthwise conv(4) + bias + silu (fp32 + fp16 out) ----------
__global__ __launch_bounds__(256) void conv_silu_k(const float* __restrict__ left,
                                                   const float* __restrict__ cw,
                                                   const float* __restrict__ cb,
                                                   float* __restrict__ xc,
                                                   half_t* __restrict__ xch) {
  const int idx = blockIdx.x * 256 + threadIdx.x;  // over TOK*DI
  const int d = idx & (DI - 1);
  const int bt = idx >> 11;
  const int t = bt & (LL - 1);
  const float4 wv = *(const float4*)(cw + (size_t)d * 4);
  float acc = cb[d];
  const size_t base = (size_t)idx;
  if (t >= 3) {
    acc += left[base - 3 * DI] * wv.x + left[base - 2 * DI] * wv.y +
           left[base - DI] * wv.z + left[base] * wv.w;
  } else {
    acc += left[base] * wv.w;
    if (t >= 1) acc += left[base - DI] * wv.z;
    if (t >= 2) acc += left[base - 2 * DI] * wv.y;
  }
  const float v = silu_f(acc);
  xc[base] = v;
  xch[base] = (half_t)v;
}

// ---------- selective scan: DPP reduce, packed LDS, prefetch pipeline ----------
#define ST 32
__global__ __launch_bounds__(256) void scan_k(const float* __restrict__ delta,
                                              const float* __restrict__ xc,
                                              const float* __restrict__ gate,
                                              const float* __restrict__ bcp,
                                              const float* __restrict__ A_log,
                                              float* __restrict__ y) {
  __shared__ float dx2[16 * 68];
  __shared__ float bcs[ST * 32];
  __shared__ float ys[ST * 16];
  const int tid = threadIdx.x;
  const int b  = blockIdx.x >> 7;
  const int d0 = (blockIdx.x & 127) << 4;
  const int n  = tid & 15;
  const int ch = tid >> 4;
  const float An = -softplus_f(A_log[n]);

  const int t_a = tid >> 4, c_a = tid & 15;
  const int t_b = t_a + 16;

  float h = 0.f;
  const size_t batch_base = (size_t)b * LL * DI + d0;
  const size_t batch_bc   = (size_t)b * LL * 32;

  size_t rb_cur = batch_base;
  float g0, g1;
  {
    const size_t ra = rb_cur + (size_t)t_a * DI + c_a;
    const size_t rbx = rb_cur + (size_t)t_b * DI + c_a;
    const float d0v = delta[ra], x0v = xc[ra];
    const float d1v = delta[rbx], x1v = xc[rbx];
    g0 = gate[ra]; g1 = gate[rbx];
    const float2 b0 = *(const float2*)&bcp[batch_bc + (size_t)t_a * 32 + 2 * c_a];
    const float2 b1 = *(const float2*)&bcp[batch_bc + (size_t)t_b * 32 + 2 * c_a];
    *(float2*)&dx2[c_a * 68 + t_a * 2] = make_float2(d0v, x0v);
    *(float2*)&dx2[c_a * 68 + t_b * 2] = make_float2(d1v, x1v);
    *(float2*)&bcs[t_a * 32 + 2 * c_a] = b0;
    *(float2*)&bcs[t_b * 32 + 2 * c_a] = b1;
  }
  __syncthreads();

  for (int it = 0; it < LL / ST; ++it) {
    float nd0, nx0, ng0, nd1, nx1, ng1;
    float2 nb0, nb1;
    const size_t rb_nxt = batch_base + (size_t)(it + 1) * ST * DI;
    if (it + 1 < LL / ST) {
      const size_t ra = rb_nxt + (size_t)t_a * DI + c_a;
      const size_t rbx = rb_nxt + (size_t)t_b * DI + c_a;
      nd0 = delta[ra]; nx0 = xc[ra]; ng0 = gate[ra];
      nd1 = delta[rbx]; nx1 = xc[rbx]; ng1 = gate[rbx];
      const size_t bcb = batch_bc + (size_t)(it + 1) * ST * 32;
      nb0 = *(const float2*)&bcp[bcb + (size_t)t_a * 32 + 2 * c_a];
      nb1 = *(const float2*)&bcp[bcb + (size_t)t_b * 32 + 2 * c_a];
    }

    const float* dxp = &dx2[ch * 68];
#pragma unroll
    for (int tt = 0; tt < ST; tt += 2) {
      const float4 v = *(const float4*)&dxp[tt * 2];
      const float2 bc0 = *(const float2*)&bcs[tt * 32 + 2 * n];
      const float2 bc1 = *(const float2*)&bcs[(tt + 1) * 32 + 2 * n];
      float ab = __expf(v.x * An);
      h = fmaf(ab, h, v.x * v.y * bc0.x);
      float p = h * bc0.y;
      p = DPP_ADD(p, 0x111); p = DPP_ADD(p, 0x112);
      p = DPP_ADD(p, 0x114); p = DPP_ADD(p, 0x118);
      if (n == 15) ys[tt * 16 + ch] = p;
      ab = __expf(v.z * An);
      h = fmaf(ab, h, v.z * v.w * bc1.x);
      p = h * bc1.y;
      p = DPP_ADD(p, 0x111); p = DPP_ADD(p, 0x112);
      p = DPP_ADD(p, 0x114); p = DPP_ADD(p, 0x118);
      if (n == 15) ys[(tt + 1) * 16 + ch] = p;
    }
    __syncthreads();

    if (it + 1 < LL / ST) {
      *(float2*)&dx2[c_a * 68 + t_a * 2] = make_float2(nd0, nx0);
      *(float2*)&dx2[c_a * 68 + t_b * 2] = make_float2(nd1, nx1);
      *(float2*)&bcs[t_a * 32 + 2 * c_a] = nb0;
      *(float2*)&bcs[t_b * 32 + 2 * c_a] = nb1;
    }
    y[rb_cur + (size_t)t_a * DI + c_a] = ys[t_a * 16 + c_a] * g0;
    y[rb_cur + (size_t)t_b * DI + c_a] = ys[t_b * 16 + c_a] * g1;
    g0 = ng0; g1 = ng1;
    rb_cur = rb_nxt;
    __syncthreads();
  }
}

// ---------- layernorm over d_inner (fp16 out for MFMA consumer) ----------
__global__ __launch_bounds__(256) void ln_k(const float* __restrict__ y,
                                            const float* __restrict__ gam,
                                            const float* __restrict__ bet,
                                            half_t* __restrict__ outn) {
  const int row = blockIdx.x;
  const int tid = threadIdx.x;
  const float* yr = y + (size_t)row * DI;
  const float4 v0 = ((const float4*)yr)[tid];
  const float4 v1 = ((const float4*)yr)[tid + 256];
  float s = v0.x + v0.y + v0.z + v0.w + v1.x + v1.y + v1.z + v1.w;
  float q = v0.x * v0.x + v0.y * v0.y + v0.z * v0.z + v0.w * v0.w +
            v1.x * v1.x + v1.y * v1.y + v1.z * v1.z + v1.w * v1.w;
  for (int off = 32; off > 0; off >>= 1) {
    s += __shfl_down(s, off);
    q += __shfl_down(q, off);
  }
  __shared__ float sred[4], qred[4];
  const int wid = tid >> 6;
  if ((tid & 63) == 0) { sred[wid] = s; qred[wid] = q; }
  __syncthreads();
  s = sred[0] + sred[1] + sred[2] + sred[3];
  q = qred[0] + qred[1] + qred[2] + qred[3];
  const float mu = s * (1.f / DI);
  const float rs = rsqrtf(q * (1.f / DI) - mu * mu + 1e-5f);
  half_t* orow = outn + (size_t)row * DI;
  const int c0 = tid * 4, c1 = (tid + 256) * 4;
  f16x4 o;
  o[0] = (half_t)((v0.x - mu) * rs * gam[c0 + 0] + bet[c0 + 0]);
  o[1] = (half_t)((v0.y - mu) * rs * gam[c0 + 1] + bet[c0 + 1]);
  o[2] = (half_t)((v0.z - mu) * rs * gam[c0 + 2] + bet[c0 + 2]);
  o[3] = (half_t)((v0.w - mu) * rs * gam[c0 + 3] + bet[c0 + 3]);
  ((f16x4*)orow)[tid] = o;
  o[0] = (half_t)((v1.x - mu) * rs * gam[c1 + 0] + bet[c1 + 0]);
  o[1] = (half_t)((v1.y - mu) * rs * gam[c1 + 1] + bet[c1 + 1]);
  o[2] = (half_t)((v1.z - mu) * rs * gam[c1 + 2] + bet[c1 + 2]);
  o[3] = (half_t)((v1.w - mu) * rs * gam[c1 + 3] + bet[c1 + 3]);
  ((f16x4*)orow)[tid + 256] = o;
}

// ---------- host launch ----------
extern "C" void kernel_launch(void* const* d_in, const int* in_sizes, int n_in,
                              void* d_out, int out_size, void* d_ws, size_t ws_size,
                              hipStream_t stream) {
  const float* x       = (const float*)d_in[0];
  const float* W_left  = (const float*)d_in[1];
  const float* conv_w  = (const float*)d_in[2];
  const float* conv_b  = (const float*)d_in[3];
  const float* W_delta = (const float*)d_in[4];
  const float* b_delta = (const float*)d_in[5];
  const float* W_B     = (const float*)d_in[6];
  const float* W_C     = (const float*)d_in[7];
  const float* A_log   = (const float*)d_in[8];
  const float* W_right = (const float*)d_in[9];
  const float* ln_g    = (const float*)d_in[10];
  const float* ln_b    = (const float*)d_in[11];
  const float* W_out   = (const float*)d_in[12];

  float* buf = nullptr;
  hipGetSymbolAddress((void**)&buf, HIP_SYMBOL(g_buf));
  half_t* xh   = (half_t*)(buf + 0);
  half_t* wlgh = (half_t*)(buf + 4194304);   // [W_left;W_right] 4096x1024 fp16
  half_t* wrh  = (half_t*)(buf + 5242880);
  half_t* wdh  = (half_t*)(buf + 6291456);
  half_t* wdl  = (half_t*)(buf + 8388608);
  half_t* woh  = (half_t*)(buf + 10485760);
  float* left  = buf + 11534336;
  float* xc    = buf + 28311552;
  half_t* xch  = (half_t*)(buf + 45088768);
  float* dlt   = buf + 61865984;
  float* gate  = buf + 78643200;
  float* yv    = buf + 95420416;
  half_t* nrmh = (half_t*)(buf + 112197632);
  float* bc    = buf + 120586240;
  half_t* wbch = (half_t*)(buf + 120848384);

  // fp32 -> fp16 staging
  f2h_k<<<8192, 256, 0, stream>>>(x, xh, TOK * DM / 4);
  f2h_k<<<2048, 256, 0, stream>>>(W_left, wlgh, DI * DM / 4);
  f2h_k<<<2048, 256, 0, stream>>>(W_right, wrh, DI * DM / 4);
  f2h_k<<<2048, 256, 0, stream>>>(W_out, woh, DM * DI / 4);
  f2h2_k<<<4096, 256, 0, stream>>>(W_delta, wdh, wdl, DI * DI / 4);
  f2h_k<<<32, 256, 0, stream>>>(W_B, wbch, NS * DI / 4);
  f2h_k<<<32, 256, 0, stream>>>(W_C, wbch + NS * DI, NS * DI / 4);

  // left = x @ W_left^T ; gate = silu(x @ W_right^T)  -- fused, N=4096
  gemm_mfma_lg<<<dim3(2 * DI / 128, TOK / 128), 256, 0, stream>>>(xh, wlgh, left, gate);
  // xc = silu(causal_conv(left))  (fp32 + fp16)
  conv_silu_k<<<TOK * DI / 256, 256, 0, stream>>>(left, conv_w, conv_b, xc, xch);
  // delta = clip(softplus(xc @ W_delta^T + b_delta))  [BK=64 counted-vmcnt dbuf]
  gemm_mfma_split<<<dim3(DI / 128, TOK / 256), 512, 0, stream>>>(xch, wdh, wdl, b_delta, dlt, TOK, DI, DI);
  // B/C projections via MFMA (interleaved output)
  bc_mfma<<<TOK / 128, 256, 0, stream>>>(xch, wbch, bc);
  // selective scan with fused gate (DPP reduce + prefetch pipeline)
  scan_k<<<512, 256, 0, stream>>>(dlt, xc, gate, bc, A_log, yv);
  // layernorm -> fp16
  ln_k<<<TOK, 256, 0, stream>>>(yv, ln_g, ln_b, nrmh);
  // out = nrm @ W_out^T  (fp32 store to d_out)
  gemm_mfma<0><<<dim3(DM / 128, TOK / 128), 256, 0, stream>>>(nrmh, woh, nullptr, (float*)d_out, TOK, DM, DI);
}

// Round 6
// 908.988 us; speedup vs baseline: 1.1143x; 1.0648x over previous
//
#include <hip/hip_runtime.h>
#include <cstddef>

#define LL 2048
#define TOK 8192   // B*L = 4*2048
#define DM 1024
#define DI 2048
#define NS 16

typedef _Float16 half_t;
typedef __attribute__((ext_vector_type(8))) _Float16 f16x8;
typedef __attribute__((ext_vector_type(4))) _Float16 f16x4;
typedef __attribute__((ext_vector_type(4))) float f32x4;

// ---------- helpers ----------
__device__ __forceinline__ float softplus_f(float x) {
  return fmaxf(x, 0.f) + log1pf(__expf(-fabsf(x)));
}
__device__ __forceinline__ float silu_f(float x) {
  return x / (1.f + __expf(-x));
}
__device__ __forceinline__ void gload_lds16(const void* g, void* l) {
  __builtin_amdgcn_global_load_lds((const __attribute__((address_space(1))) void*)g,
                                   (__attribute__((address_space(3))) void*)l, 16, 0, 0);
}
// DPP row_shr add: after ctrl 0x111,0x112,0x114,0x118 lane15 of each row16 holds the row sum
#define DPP_ADD(v, ctrl) \
  ((v) + __int_as_float(__builtin_amdgcn_update_dpp(0, __float_as_int(v), (ctrl), 0xf, 0xf, true)))

// ---------- static scratch (float units) ----------
//  xh    @ 0            x fp16
//  wlgh  @ 4,194,304    [W_left;W_right] fp16 [4096][1024]
//  wdf   @ 6,291,456    [W_delta;W_B;W_C;zeros] fp16 [2176][2048] (2,228,224 fl)
//  woh   @ 10,485,760   W_out fp16
//  left  @ 11,534,336
//  xc    @ 28,311,552
//  xch   @ 45,088,768   xc fp16
//  dlt   @ 61,865,984
//  gate  @ 78,643,200
//  y     @ 95,420,416
//  nrmh  @ 112,197,632  LN out fp16
//  bc    @ 120,586,240  packed: [row][2n]=B_n, [2n+1]=C_n
__device__ float g_buf[120881152];

// ---------- fp32 -> fp16 staging ----------
__global__ __launch_bounds__(256) void f2h_k(const float* __restrict__ in,
                                             half_t* __restrict__ out, int n4) {
  const int i = blockIdx.x * 256 + threadIdx.x;
  if (i >= n4) return;
  const float4 v = ((const float4*)in)[i];
  f16x4 o;
  o[0] = (half_t)v.x; o[1] = (half_t)v.y; o[2] = (half_t)v.z; o[3] = (half_t)v.w;
  ((f16x4*)out)[i] = o;
}

// ---------- fp16 zero fill (pad rows of the fused delta/BC weight) ----------
__global__ __launch_bounds__(256) void zh_k(half_t* __restrict__ out, int n4) {
  const int i = blockIdx.x * 256 + threadIdx.x;
  if (i >= n4) return;
  f16x4 o;
  o[0] = (half_t)0.f; o[1] = (half_t)0.f; o[2] = (half_t)0.f; o[3] = (half_t)0.f;
  ((f16x4*)out)[i] = o;
}

// ---------- fp16 MFMA GEMM: C[M,N] = act(A[M,K] @ W[N,K]^T + bias), fp32 out --
template <int ACT>   // 0 none, 1 silu
__global__ __launch_bounds__(256) void gemm_mfma(const half_t* __restrict__ A,
                                                 const half_t* __restrict__ W,
                                                 const float* __restrict__ bias,
                                                 float* __restrict__ C,
                                                 int M, int N, int K) {
  __shared__ half_t lA[4096];   // 8 KB
  __shared__ half_t lB[4096];   // 8 KB
  const int tid = threadIdx.x;
  const int bm0 = blockIdx.y * 128, bn0 = blockIdx.x * 128;
  const int lane = tid & 63, wave = tid >> 6;
  const int q = lane >> 4, mr = lane & 15;
  const int wm = (wave >> 1) * 64, wn = (wave & 1) * 64;
  const int flat0 = tid, flat1 = tid + 256;
  const int kc0 = flat0 >> 7, r0 = flat0 & 127;
  const int kc1 = flat1 >> 7, r1 = flat1 & 127;

  f32x4 acc[4][4];
#pragma unroll
  for (int i = 0; i < 4; ++i)
#pragma unroll
    for (int j = 0; j < 4; ++j) acc[i][j] = (f32x4){0.f, 0.f, 0.f, 0.f};

  for (int k0 = 0; k0 < K; k0 += 32) {
    gload_lds16(A + (size_t)(bm0 + r0) * K + k0 + kc0 * 8, lA + (size_t)flat0 * 8);
    gload_lds16(A + (size_t)(bm0 + r1) * K + k0 + kc1 * 8, lA + (size_t)flat1 * 8);
    gload_lds16(W + (size_t)(bn0 + r0) * K + k0 + kc0 * 8, lB + (size_t)flat0 * 8);
    gload_lds16(W + (size_t)(bn0 + r1) * K + k0 + kc1 * 8, lB + (size_t)flat1 * 8);
    __syncthreads();
    f16x8 af[4], bg[4];
#pragma unroll
    for (int t = 0; t < 4; ++t) {
      af[t] = *(const f16x8*)(lA + ((q << 10) + ((wm + t * 16 + mr) << 3)));
      bg[t] = *(const f16x8*)(lB + ((q << 10) + ((wn + t * 16 + mr) << 3)));
    }
#pragma unroll
    for (int i = 0; i < 4; ++i)
#pragma unroll
      for (int j = 0; j < 4; ++j)
        acc[i][j] = __builtin_amdgcn_mfma_f32_16x16x32_f16(af[i], bg[j], acc[i][j], 0, 0, 0);
    __syncthreads();
  }

#pragma unroll
  for (int i = 0; i < 4; ++i) {
#pragma unroll
    for (int j = 0; j < 4; ++j) {
      const int col = bn0 + wn + j * 16 + mr;
      const float bv = bias ? bias[col] : 0.f;
#pragma unroll
      for (int r = 0; r < 4; ++r) {
        const int row = bm0 + wm + i * 16 + q * 4 + r;
        float v = acc[i][j][r] + bv;
        if (ACT == 1) v = silu_f(v);
        C[(size_t)row * N + col] = v;
      }
    }
  }
}

// ---------- fused left+gate GEMM: W = [W_left;W_right] (4096 x 1024) ----------
__global__ __launch_bounds__(256) void gemm_mfma_lg(const half_t* __restrict__ A,
                                                    const half_t* __restrict__ W,
                                                    float* __restrict__ left,
                                                    float* __restrict__ gate) {
  __shared__ half_t lA[4096];
  __shared__ half_t lB[4096];
  const int tid = threadIdx.x;
  const int bm0 = blockIdx.y * 128, bn0 = blockIdx.x * 128;
  const int K = DM;
  const int lane = tid & 63, wave = tid >> 6;
  const int q = lane >> 4, mr = lane & 15;
  const int wm = (wave >> 1) * 64, wn = (wave & 1) * 64;
  const int flat1 = tid + 256;
  const int kc0 = tid >> 7, r0 = tid & 127;
  const int kc1 = flat1 >> 7, r1 = flat1 & 127;

  f32x4 acc[4][4];
#pragma unroll
  for (int i = 0; i < 4; ++i)
#pragma unroll
    for (int j = 0; j < 4; ++j) acc[i][j] = (f32x4){0.f, 0.f, 0.f, 0.f};

  for (int k0 = 0; k0 < K; k0 += 32) {
    gload_lds16(A + (size_t)(bm0 + r0) * K + k0 + kc0 * 8, lA + (size_t)tid * 8);
    gload_lds16(A + (size_t)(bm0 + r1) * K + k0 + kc1 * 8, lA + (size_t)flat1 * 8);
    gload_lds16(W + (size_t)(bn0 + r0) * K + k0 + kc0 * 8, lB + (size_t)tid * 8);
    gload_lds16(W + (size_t)(bn0 + r1) * K + k0 + kc1 * 8, lB + (size_t)flat1 * 8);
    __syncthreads();
    f16x8 af[4], bg[4];
#pragma unroll
    for (int t = 0; t < 4; ++t) {
      af[t] = *(const f16x8*)(lA + ((q << 10) + ((wm + t * 16 + mr) << 3)));
      bg[t] = *(const f16x8*)(lB + ((q << 10) + ((wn + t * 16 + mr) << 3)));
    }
#pragma unroll
    for (int i = 0; i < 4; ++i)
#pragma unroll
      for (int j = 0; j < 4; ++j)
        acc[i][j] = __builtin_amdgcn_mfma_f32_16x16x32_f16(af[i], bg[j], acc[i][j], 0, 0, 0);
    __syncthreads();
  }

  const int is_gate = (bn0 >= DI);
  float* out = is_gate ? gate : left;
  const int cb = bn0 - (is_gate ? DI : 0);
#pragma unroll
  for (int i = 0; i < 4; ++i) {
#pragma unroll
    for (int j = 0; j < 4; ++j) {
      const int col = cb + wn + j * 16 + mr;
#pragma unroll
      for (int r = 0; r < 4; ++r) {
        const int row = bm0 + wm + i * 16 + q * 4 + r;
        float v = acc[i][j][r];
        if (is_gate) v = silu_f(v);
        out[(size_t)row * DI + col] = v;
      }
    }
  }
}

// ---------- fused delta + B/C GEMM, 256x128 tile, 512 threads (8 waves) ------
// Single-term fp16 (Wl dropped: the A-side (xch) is already fp16-rounded, so
// the hi/lo W-split only removed one of two equal error sources -- <=sqrt(2)
// marginal precision for 2x MFMA + 1.33x staging).  W = [W_delta; W_B; W_C;
// zero-pad] as [2176][2048] fp16; grid x = 17 col-blocks.  Blocks bn0<2048
// write delta = clip(softplus(acc+bias)); the bn0==2048 block writes the
// interleaved bc buffer (cols 0..15 = B_n -> slot 2n, 16..31 = C_n -> 2n+1),
// replacing the separate bc_mfma dispatch (which re-staged all of xch).
// Proven R0 structure: single-buffer 2-barrier, 4Mx2N waves, acc[4][4],
// staged 24 KB / K-step (was 32), 2 blocks/CU.
__global__ __launch_bounds__(512, 4) void gemm_delta_bc(const half_t* __restrict__ A,
                                                        const half_t* __restrict__ W,
                                                        const float* __restrict__ bias,
                                                        float* __restrict__ dlt,
                                                        float* __restrict__ bcout) {
  __shared__ half_t lA[8192];   // [kc4][256][8]  16 KB
  __shared__ half_t lB[4096];   // [kc4][128][8]   8 KB
  const int tid = threadIdx.x;
  const int bm0 = blockIdx.y * 256, bn0 = blockIdx.x * 128;
  const int K = DI;
  const int lane = tid & 63, wave = tid >> 6;
  const int q = lane >> 4, mr = lane & 15;
  const int wm = (wave >> 1) * 64, wn = (wave & 1) * 64;
  // A staging: 1024 chunks, 2 per thread
  const int aflat1 = tid + 512;
  const int akc0 = tid >> 8, ar0 = tid & 255;
  const int akc1 = aflat1 >> 8, ar1 = aflat1 & 255;
  // W staging: 512 chunks, 1 per thread
  const int wkc = tid >> 7, wr = tid & 127;

  f32x4 acc[4][4];
#pragma unroll
  for (int i = 0; i < 4; ++i)
#pragma unroll
    for (int j = 0; j < 4; ++j) acc[i][j] = (f32x4){0.f, 0.f, 0.f, 0.f};

  for (int k0 = 0; k0 < K; k0 += 32) {
    gload_lds16(A + (size_t)(bm0 + ar0) * K + k0 + akc0 * 8, lA + (size_t)tid * 8);
    gload_lds16(A + (size_t)(bm0 + ar1) * K + k0 + akc1 * 8, lA + (size_t)aflat1 * 8);
    gload_lds16(W + (size_t)(bn0 + wr) * K + k0 + wkc * 8, lB + (size_t)tid * 8);
    __syncthreads();
    f16x8 ah[4], bg[4];
#pragma unroll
    for (int t = 0; t < 4; ++t) {
      const int ao = (q << 11) + ((wm + t * 16 + mr) << 3);   // q*256*8
      const int bo = (q << 10) + ((wn + t * 16 + mr) << 3);   // q*128*8
      ah[t] = *(const f16x8*)(lA + ao);
      bg[t] = *(const f16x8*)(lB + bo);
    }
    __builtin_amdgcn_s_setprio(1);
#pragma unroll
    for (int i = 0; i < 4; ++i)
#pragma unroll
      for (int j = 0; j < 4; ++j)
        acc[i][j] = __builtin_amdgcn_mfma_f32_16x16x32_f16(ah[i], bg[j], acc[i][j], 0, 0, 0);
    __builtin_amdgcn_s_setprio(0);
    __syncthreads();
  }

  if (bn0 < DI) {
    // delta path: clip(softplus(acc + bias))
#pragma unroll
    for (int i = 0; i < 4; ++i) {
#pragma unroll
      for (int j = 0; j < 4; ++j) {
        const int col = bn0 + wn + j * 16 + mr;
        const float bv = bias[col];
#pragma unroll
        for (int r = 0; r < 4; ++r) {
          const int row = bm0 + wm + i * 16 + q * 4 + r;
          float v = softplus_f(acc[i][j][r] + bv);
          v = fminf(fmaxf(v, 1e-4f), 10.f);
          dlt[(size_t)row * DI + col] = v;
        }
      }
    }
  } else {
    // B/C path: local col c in [0,32): c<16 -> B_c at slot 2c, else C_(c-16)
    // at slot 2(c-16)+1.  Cols >= 32 hit the zero-pad rows; skip.
#pragma unroll
    for (int i = 0; i < 4; ++i) {
#pragma unroll
      for (int j = 0; j < 4; ++j) {
        const int c = wn + j * 16 + mr;
        if (c < 32) {
          const int slot = (c < 16) ? (2 * c) : (2 * (c - 16) + 1);
#pragma unroll
          for (int r = 0; r < 4; ++r) {
            const int row = bm0 + wm + i * 16 + q * 4 + r;
            bcout[(size_t)row * 32 + slot] = acc[i][j][r];
          }
        }
      }
    }
  }
}

// ---------- causal depthwise conv(4) + bias + silu (fp32 + fp16 out) ----------
__global__ __launch_bounds__(256) void conv_silu_k(const float* __restrict__ left,
                                                   const float* __restrict__ cw,
                                                   const float* __restrict__ cb,
                                                   float* __restrict__ xc,
                                                   half_t* __restrict__ xch) {
  const int idx = blockIdx.x * 256 + threadIdx.x;  // over TOK*DI
  const int d = idx & (DI - 1);
  const int bt = idx >> 11;
  const int t = bt & (LL - 1);
  const float4 wv = *(const float4*)(cw + (size_t)d * 4);
  float acc = cb[d];
  const size_t base = (size_t)idx;
  if (t >= 3) {
    acc += left[base - 3 * DI] * wv.x + left[base - 2 * DI] * wv.y +
           left[base - DI] * wv.z + left[base] * wv.w;
  } else {
    acc += left[base] * wv.w;
    if (t >= 1) acc += left[base - DI] * wv.z;
    if (t >= 2) acc += left[base - 2 * DI] * wv.y;
  }
  const float v = silu_f(acc);
  xc[base] = v;
  xch[base] = (half_t)v;
}

// ---------- selective scan: DPP reduce, packed LDS, prefetch pipeline ----------
#define ST 32
__global__ __launch_bounds__(256) void scan_k(const float* __restrict__ delta,
                                              const float* __restrict__ xc,
                                              const float* __restrict__ gate,
                                              const float* __restrict__ bcp,
                                              const float* __restrict__ A_log,
                                              float* __restrict__ y) {
  __shared__ float dx2[16 * 68];
  __shared__ float bcs[ST * 32];
  __shared__ float ys[ST * 16];
  const int tid = threadIdx.x;
  const int b  = blockIdx.x >> 7;
  const int d0 = (blockIdx.x & 127) << 4;
  const int n  = tid & 15;
  const int ch = tid >> 4;
  const float An = -softplus_f(A_log[n]);

  const int t_a = tid >> 4, c_a = tid & 15;
  const int t_b = t_a + 16;

  float h = 0.f;
  const size_t batch_base = (size_t)b * LL * DI + d0;
  const size_t batch_bc   = (size_t)b * LL * 32;

  size_t rb_cur = batch_base;
  float g0, g1;
  {
    const size_t ra = rb_cur + (size_t)t_a * DI + c_a;
    const size_t rbx = rb_cur + (size_t)t_b * DI + c_a;
    const float d0v = delta[ra], x0v = xc[ra];
    const float d1v = delta[rbx], x1v = xc[rbx];
    g0 = gate[ra]; g1 = gate[rbx];
    const float2 b0 = *(const float2*)&bcp[batch_bc + (size_t)t_a * 32 + 2 * c_a];
    const float2 b1 = *(const float2*)&bcp[batch_bc + (size_t)t_b * 32 + 2 * c_a];
    *(float2*)&dx2[c_a * 68 + t_a * 2] = make_float2(d0v, x0v);
    *(float2*)&dx2[c_a * 68 + t_b * 2] = make_float2(d1v, x1v);
    *(float2*)&bcs[t_a * 32 + 2 * c_a] = b0;
    *(float2*)&bcs[t_b * 32 + 2 * c_a] = b1;
  }
  __syncthreads();

  for (int it = 0; it < LL / ST; ++it) {
    float nd0, nx0, ng0, nd1, nx1, ng1;
    float2 nb0, nb1;
    const size_t rb_nxt = batch_base + (size_t)(it + 1) * ST * DI;
    if (it + 1 < LL / ST) {
      const size_t ra = rb_nxt + (size_t)t_a * DI + c_a;
      const size_t rbx = rb_nxt + (size_t)t_b * DI + c_a;
      nd0 = delta[ra]; nx0 = xc[ra]; ng0 = gate[ra];
      nd1 = delta[rbx]; nx1 = xc[rbx]; ng1 = gate[rbx];
      const size_t bcb = batch_bc + (size_t)(it + 1) * ST * 32;
      nb0 = *(const float2*)&bcp[bcb + (size_t)t_a * 32 + 2 * c_a];
      nb1 = *(const float2*)&bcp[bcb + (size_t)t_b * 32 + 2 * c_a];
    }

    const float* dxp = &dx2[ch * 68];
#pragma unroll
    for (int tt = 0; tt < ST; tt += 2) {
      const float4 v = *(const float4*)&dxp[tt * 2];
      const float2 bc0 = *(const float2*)&bcs[tt * 32 + 2 * n];
      const float2 bc1 = *(const float2*)&bcs[(tt + 1) * 32 + 2 * n];
      float ab = __expf(v.x * An);
      h = fmaf(ab, h, v.x * v.y * bc0.x);
      float p = h * bc0.y;
      p = DPP_ADD(p, 0x111); p = DPP_ADD(p, 0x112);
      p = DPP_ADD(p, 0x114); p = DPP_ADD(p, 0x118);
      if (n == 15) ys[tt * 16 + ch] = p;
      ab = __expf(v.z * An);
      h = fmaf(ab, h, v.z * v.w * bc1.x);
      p = h * bc1.y;
      p = DPP_ADD(p, 0x111); p = DPP_ADD(p, 0x112);
      p = DPP_ADD(p, 0x114); p = DPP_ADD(p, 0x118);
      if (n == 15) ys[(tt + 1) * 16 + ch] = p;
    }
    __syncthreads();

    if (it + 1 < LL / ST) {
      *(float2*)&dx2[c_a * 68 + t_a * 2] = make_float2(nd0, nx0);
      *(float2*)&dx2[c_a * 68 + t_b * 2] = make_float2(nd1, nx1);
      *(float2*)&bcs[t_a * 32 + 2 * c_a] = nb0;
      *(float2*)&bcs[t_b * 32 + 2 * c_a] = nb1;
    }
    y[rb_cur + (size_t)t_a * DI + c_a] = ys[t_a * 16 + c_a] * g0;
    y[rb_cur + (size_t)t_b * DI + c_a] = ys[t_b * 16 + c_a] * g1;
    g0 = ng0; g1 = ng1;
    rb_cur = rb_nxt;
    __syncthreads();
  }
}

// ---------- layernorm over d_inner (fp16 out for MFMA consumer) ----------
__global__ __launch_bounds__(256) void ln_k(const float* __restrict__ y,
                                            const float* __restrict__ gam,
                                            const float* __restrict__ bet,
                                            half_t* __restrict__ outn) {
  const int row = blockIdx.x;
  const int tid = threadIdx.x;
  const float* yr = y + (size_t)row * DI;
  const float4 v0 = ((const float4*)yr)[tid];
  const float4 v1 = ((const float4*)yr)[tid + 256];
  float s = v0.x + v0.y + v0.z + v0.w + v1.x + v1.y + v1.z + v1.w;
  float q = v0.x * v0.x + v0.y * v0.y + v0.z * v0.z + v0.w * v0.w +
            v1.x * v1.x + v1.y * v1.y + v1.z * v1.z + v1.w * v1.w;
  for (int off = 32; off > 0; off >>= 1) {
    s += __shfl_down(s, off);
    q += __shfl_down(q, off);
  }
  __shared__ float sred[4], qred[4];
  const int wid = tid >> 6;
  if ((tid & 63) == 0) { sred[wid] = s; qred[wid] = q; }
  __syncthreads();
  s = sred[0] + sred[1] + sred[2] + sred[3];
  q = qred[0] + qred[1] + qred[2] + qred[3];
  const float mu = s * (1.f / DI);
  const float rs = rsqrtf(q * (1.f / DI) - mu * mu + 1e-5f);
  half_t* orow = outn + (size_t)row * DI;
  const int c0 = tid * 4, c1 = (tid + 256) * 4;
  f16x4 o;
  o[0] = (half_t)((v0.x - mu) * rs * gam[c0 + 0] + bet[c0 + 0]);
  o[1] = (half_t)((v0.y - mu) * rs * gam[c0 + 1] + bet[c0 + 1]);
  o[2] = (half_t)((v0.z - mu) * rs * gam[c0 + 2] + bet[c0 + 2]);
  o[3] = (half_t)((v0.w - mu) * rs * gam[c0 + 3] + bet[c0 + 3]);
  ((f16x4*)orow)[tid] = o;
  o[0] = (half_t)((v1.x - mu) * rs * gam[c1 + 0] + bet[c1 + 0]);
  o[1] = (half_t)((v1.y - mu) * rs * gam[c1 + 1] + bet[c1 + 1]);
  o[2] = (half_t)((v1.z - mu) * rs * gam[c1 + 2] + bet[c1 + 2]);
  o[3] = (half_t)((v1.w - mu) * rs * gam[c1 + 3] + bet[c1 + 3]);
  ((f16x4*)orow)[tid + 256] = o;
}

// ---------- host launch ----------
extern "C" void kernel_launch(void* const* d_in, const int* in_sizes, int n_in,
                              void* d_out, int out_size, void* d_ws, size_t ws_size,
                              hipStream_t stream) {
  const float* x       = (const float*)d_in[0];
  const float* W_left  = (const float*)d_in[1];
  const float* conv_w  = (const float*)d_in[2];
  const float* conv_b  = (const float*)d_in[3];
  const float* W_delta = (const float*)d_in[4];
  const float* b_delta = (const float*)d_in[5];
  const float* W_B     = (const float*)d_in[6];
  const float* W_C     = (const float*)d_in[7];
  const float* A_log   = (const float*)d_in[8];
  const float* W_right = (const float*)d_in[9];
  const float* ln_g    = (const float*)d_in[10];
  const float* ln_b    = (const float*)d_in[11];
  const float* W_out   = (const float*)d_in[12];

  float* buf = nullptr;
  hipGetSymbolAddress((void**)&buf, HIP_SYMBOL(g_buf));
  half_t* xh   = (half_t*)(buf + 0);
  half_t* wlgh = (half_t*)(buf + 4194304);   // [W_left;W_right] 4096x1024 fp16
  half_t* wrh  = (half_t*)(buf + 5242880);
  half_t* wdf  = (half_t*)(buf + 6291456);   // [W_delta;W_B;W_C;zeros] 2176x2048 fp16
  half_t* woh  = (half_t*)(buf + 10485760);
  float* left  = buf + 11534336;
  float* xc    = buf + 28311552;
  half_t* xch  = (half_t*)(buf + 45088768);
  float* dlt   = buf + 61865984;
  float* gate  = buf + 78643200;
  float* yv    = buf + 95420416;
  half_t* nrmh = (half_t*)(buf + 112197632);
  float* bc    = buf + 120586240;

  // fp32 -> fp16 staging
  f2h_k<<<8192, 256, 0, stream>>>(x, xh, TOK * DM / 4);
  f2h_k<<<2048, 256, 0, stream>>>(W_left, wlgh, DI * DM / 4);
  f2h_k<<<2048, 256, 0, stream>>>(W_right, wrh, DI * DM / 4);
  f2h_k<<<2048, 256, 0, stream>>>(W_out, woh, DM * DI / 4);
  // fused delta/BC weight: rows 0..2047 = W_delta, 2048..2063 = W_B,
  // 2064..2079 = W_C, 2080..2175 = zeros
  f2h_k<<<4096, 256, 0, stream>>>(W_delta, wdf, DI * DI / 4);
  f2h_k<<<32, 256, 0, stream>>>(W_B, wdf + (size_t)DI * DI, NS * DI / 4);
  f2h_k<<<32, 256, 0, stream>>>(W_C, wdf + (size_t)(DI + NS) * DI, NS * DI / 4);
  zh_k<<<192, 256, 0, stream>>>(wdf + (size_t)(DI + 2 * NS) * DI, 96 * DI / 4);

  // left = x @ W_left^T ; gate = silu(x @ W_right^T)  -- fused, N=4096
  gemm_mfma_lg<<<dim3(2 * DI / 128, TOK / 128), 256, 0, stream>>>(xh, wlgh, left, gate);
  // xc = silu(causal_conv(left))  (fp32 + fp16)
  conv_silu_k<<<TOK * DI / 256, 256, 0, stream>>>(left, conv_w, conv_b, xc, xch);
  // delta = clip(softplus(xc @ W_delta^T + b)) and bc = xc @ [W_B;W_C]^T, fused
  gemm_delta_bc<<<dim3(17, TOK / 256), 512, 0, stream>>>(xch, wdf, b_delta, dlt, bc);
  // selective scan with fused gate (DPP reduce + prefetch pipeline)
  scan_k<<<512, 256, 0, stream>>>(dlt, xc, gate, bc, A_log, yv);
  // layernorm -> fp16
  ln_k<<<TOK, 256, 0, stream>>>(yv, ln_g, ln_b, nrmh);
  // out = nrm @ W_out^T  (fp32 store to d_out)
  gemm_mfma<0><<<dim3(DM / 128, TOK / 128), 256, 0, stream>>>(nrmh, woh, nullptr, (float*)d_out, TOK, DM, DI);
}